// Round 12
// baseline (207.805 us; speedup 1.0000x reference)
//
#include <hip/hip_runtime.h>

#define INC  128
#define HIDC 128
#define OUTC 64

#define BSH   8        // bucket = dst >> 8 (256 nodes per bucket)
#define NBMAX 512      // supports n <= 131072
#define HB    128      // bhist blocks
#define TILE  4096     // edges per multisplit block
#define CAP   8192     // csr_build LDS col-stage capacity

typedef unsigned int  u32;
typedef unsigned short u16;
typedef short bf16x8 __attribute__((ext_vector_type(8)));
typedef float f32x4 __attribute__((ext_vector_type(4)));

static __device__ __forceinline__ u16 f2bf(float f) {
    u32 u = __builtin_bit_cast(u32, f);
    u += 0x7fffu + ((u >> 16) & 1u);
    return (u16)(u >> 16);
}
static __device__ __forceinline__ float bf_lo(u32 u) {
    return __builtin_bit_cast(float, u << 16);
}
static __device__ __forceinline__ float bf_hi(u32 u) {
    return __builtin_bit_cast(float, u & 0xffff0000u);
}

// ---------------- merged: bhist (blocks [0,HB)) + fold (blocks [HB, ...)) ----------

__global__ __launch_bounds__(256) void fold_bhist_kernel(const int* __restrict__ dst,
                                                         int* __restrict__ parts,  // [NBMAX][HB]
                                                         int E, int nb,
                                                         const float* __restrict__ W1,
                                                         const float* __restrict__ W2,
                                                         const float* __restrict__ Wfc,
                                                         const float* __restrict__ b2,
                                                         const float* __restrict__ bfc,
                                                         u16* __restrict__ W1t,
                                                         u16* __restrict__ W2ft,
                                                         float* __restrict__ b2f) {
    __shared__ int h[NBMAX];
    if (blockIdx.x < HB) {
        for (int i = threadIdx.x; i < NBMAX; i += 256) h[i] = 0;
        __syncthreads();
        const int total = HB * 256;
        for (int e = blockIdx.x * 256 + threadIdx.x; e < E; e += total)
            atomicAdd(&h[dst[e] >> BSH], 1);
        __syncthreads();
        for (int i = threadIdx.x; i < nb; i += 256) parts[i * HB + blockIdx.x] = h[i];
    } else {
        int t = (blockIdx.x - HB) * 256 + threadIdx.x;
        if (t < HIDC * HIDC) {                       // W1 transpose->bf16
            int nn = t >> 7, k = t & 127;
            W1t[nn * HIDC + k] = f2bf(W1[k * HIDC + nn]);
        } else if (t < HIDC * HIDC + HIDC * OUTC) {  // W2f fold, transposed bf16
            int u = t - HIDC * HIDC;
            int i = u >> 6, j = u & 63;
            float s = 0.f;
#pragma unroll 8
            for (int k = 0; k < OUTC; ++k) s = fmaf(W2[i * OUTC + k], Wfc[k * OUTC + j], s);
            W2ft[j * HIDC + i] = f2bf(s);
        } else if (t < HIDC * HIDC + HIDC * OUTC + OUTC) {
            int j = t - HIDC * HIDC - HIDC * OUTC;
            float s = bfc[j];
#pragma unroll 8
            for (int k = 0; k < OUTC; ++k) s = fmaf(b2[k], Wfc[k * OUTC + j], s);
            b2f[j] = s;
        }
    }
}

__global__ __launch_bounds__(512) void bscan_kernel(const int* __restrict__ parts,
                                                    int* __restrict__ bucketOff, int nb) {
    __shared__ int sums[NBMAX];
    const int tid = threadIdx.x;
    int s = 0;
    if (tid < nb) {
        const int* p = parts + tid * HB;
#pragma unroll 8
        for (int r = 0; r < HB; ++r) s += p[r];
    }
    sums[tid] = s;
    __syncthreads();
    for (int d = 1; d < NBMAX; d <<= 1) {
        int t = sums[tid];
        int a = (tid >= d) ? sums[tid - d] : 0;
        __syncthreads();
        sums[tid] = t + a;
        __syncthreads();
    }
    if (tid < nb) bucketOff[tid] = sums[tid] - s;
    if (tid == NBMAX - 1) bucketOff[nb] = sums[NBMAX - 1];
}

// ---------------- bodies for the merged GEMM1 || multisplit launch ----------------

template <int N, bool AF32, bool SCALED>
static __device__ __forceinline__ void gemm_body(char* smem, const void* __restrict__ Aptr,
                                                 const u16* __restrict__ Wt,
                                                 const float* __restrict__ dinv,
                                                 u16* __restrict__ out, int M, int bid) {
    constexpr int K = 128;
    constexpr int NC = N / 16;
    u16* Ws = (u16*)smem;   // 16B slots: slot = n*16 + (c ^ (n&7))

    const int tid = threadIdx.x;
    for (int id = tid; id < N * K / 8; id += 256) {
        int nn = id >> 4;
        int c  = id & 15;
        uint4 v = *(const uint4*)(Wt + nn * K + c * 8);
        int slot = (nn << 4) + (c ^ (nn & 7));
        *(uint4*)((char*)Ws + slot * 16) = v;
    }

    const int wave = tid >> 6;
    const int lane = tid & 63;
    const int r0   = bid * 64 + wave * 16;
    const int arow = r0 + (lane & 15);
    const int kgrp = lane >> 4;   // 0..3
    __syncthreads();

    f32x4 acc[NC];
#pragma unroll
    for (int nc = 0; nc < NC; ++nc) acc[nc] = f32x4{0.f, 0.f, 0.f, 0.f};

#pragma unroll
    for (int kc = 0; kc < 4; ++kc) {
        bf16x8 af = {0, 0, 0, 0, 0, 0, 0, 0};
        if (arow < M) {
            if constexpr (AF32) {
                const float* ap = (const float*)Aptr + (size_t)arow * K + kc * 32 + kgrp * 8;
                float4 v0 = *(const float4*)ap;
                float4 v1 = *(const float4*)(ap + 4);
                af[0] = (short)f2bf(v0.x); af[1] = (short)f2bf(v0.y);
                af[2] = (short)f2bf(v0.z); af[3] = (short)f2bf(v0.w);
                af[4] = (short)f2bf(v1.x); af[5] = (short)f2bf(v1.y);
                af[6] = (short)f2bf(v1.z); af[7] = (short)f2bf(v1.w);
            } else {
                af = *(const bf16x8*)((const u16*)Aptr + (size_t)arow * K + kc * 32 + kgrp * 8);
            }
        }
#pragma unroll
        for (int nc = 0; nc < NC; ++nc) {
            int nn = nc * 16 + (lane & 15);
            int slot = (nn << 4) + ((kc * 4 + kgrp) ^ (nn & 7));
            bf16x8 bfr = *(const bf16x8*)((const char*)Ws + slot * 16);
            acc[nc] = __builtin_amdgcn_mfma_f32_16x16x32_bf16(af, bfr, acc[nc], 0, 0, 0);
        }
    }
    // C/D: col = lane&15, row = (lane>>4)*4 + reg
#pragma unroll
    for (int reg = 0; reg < 4; ++reg) {
        int row = r0 + (lane >> 4) * 4 + reg;
        if (row <= M) {
            float sc;
            if constexpr (SCALED) sc = (row < M) ? dinv[row] : 0.f;
            else                  sc = (row < M) ? 1.f : 0.f;
#pragma unroll
            for (int nc = 0; nc < NC; ++nc)
                out[(size_t)row * N + nc * 16 + (lane & 15)] = f2bf(acc[nc][reg] * sc);
        }
    }
}

// multisplit body: bin TILE edges by dst-bucket; binned elem = src | (dst&255)<<24
static __device__ __forceinline__ void ms_body(char* smem,
                                               const int* __restrict__ src,
                                               const int* __restrict__ dst,
                                               const int* __restrict__ bucketOff,
                                               int* __restrict__ gfill,
                                               u32* __restrict__ binned,
                                               int E, int nb, int bid) {
    int2* buf   = (int2*)smem;                       // TILE*8 = 32768
    int* hist   = (int*)(smem + TILE * 8);           // NBMAX ints
    int* sbase  = hist + NBMAX;
    int* cursor = sbase + NBMAX;
    int* gposs  = cursor + NBMAX;
    int* wsum   = gposs + NBMAX;                     // 4 ints
    const int tid  = threadIdx.x;
    const int base = bid * TILE;
    const int cnt  = min(TILE, E - base);

    for (int i = tid; i < NBMAX; i += 256) hist[i] = 0;
    __syncthreads();

    int ls[16], ld[16], dg[16];
#pragma unroll
    for (int k = 0; k < 16; ++k) {
        int idx = tid + k * 256;
        if (idx < cnt) {
            ls[k] = src[base + idx];
            ld[k] = dst[base + idx];
            dg[k] = ld[k] >> BSH;
            atomicAdd(&hist[dg[k]], 1);
        } else dg[k] = -1;
    }
    __syncthreads();
    {
        const int a = hist[2 * tid], b = hist[2 * tid + 1];
        const int s = a + b;
        const int lane = tid & 63;
        int incl = s;
#pragma unroll
        for (int d = 1; d < 64; d <<= 1) {
            int t = __shfl_up(incl, d);
            if (lane >= d) incl += t;
        }
        if (lane == 63) wsum[tid >> 6] = incl;
        __syncthreads();
        const int w = tid >> 6;
        int wbase = 0;
        if (w > 0) wbase += wsum[0];
        if (w > 1) wbase += wsum[1];
        if (w > 2) wbase += wsum[2];
        const int excl = wbase + incl - s;
        sbase[2 * tid] = excl;          cursor[2 * tid] = excl;
        sbase[2 * tid + 1] = excl + a;  cursor[2 * tid + 1] = excl + a;
    }
    __syncthreads();
#pragma unroll
    for (int k = 0; k < 16; ++k) {
        if (dg[k] >= 0) {
            int p = atomicAdd(&cursor[dg[k]], 1);
            buf[p] = make_int2(ls[k], ld[k]);
        }
    }
    __syncthreads();
    for (int d = tid; d < nb; d += 256) {
        int c = cursor[d] - sbase[d];
        gposs[d] = (c > 0) ? atomicAdd(&gfill[d], c) : 0;
    }
    __syncthreads();
    for (int idx = tid; idx < cnt; idx += 256) {
        int2 e = buf[idx];
        int d = e.y >> BSH;
        binned[bucketOff[d] + gposs[d] + (idx - sbase[d])] =
            (u32)e.x | ((u32)(e.y & 255) << 24);
    }
}

#define SMEM_MERGED 41008   // max(gemm 32768, ms 32768+4*NBMAX*4+16), 16-aligned

// merged: GEMM1 (unscaled -> graw) in blocks [0,G); multisplit in blocks [G, G+MS)
__global__ __launch_bounds__(256) void gemm1_ms_kernel(const float* __restrict__ x,
                                                       const u16* __restrict__ W1t,
                                                       u16* __restrict__ graw, int M,
                                                       const int* __restrict__ src,
                                                       const int* __restrict__ dst,
                                                       const int* __restrict__ bucketOff,
                                                       int* __restrict__ gfill,
                                                       u32* __restrict__ binned,
                                                       int E, int nb, int G) {
    __shared__ __align__(16) char smem[SMEM_MERGED];
    const int b = (int)blockIdx.x;
    if (b < G) gemm_body<HIDC, true, false>(smem, x, W1t, nullptr, graw, M, b);
    else       ms_body(smem, src, dst, bucketOff, gfill, binned, E, nb, b - G);
}

__global__ __launch_bounds__(256) void gemm2_kernel(const u16* __restrict__ h1,
                                                    const u16* __restrict__ W2ft,
                                                    const float* __restrict__ dinv,
                                                    u16* __restrict__ g2, int M) {
    __shared__ __align__(16) char smem[OUTC * 128 * 2];
    gemm_body<OUTC, false, true>(smem, h1, W2ft, dinv, g2, M, (int)blockIdx.x);
}

// ---------------- csr_build: per-bucket node grouping (col + rowptr + dinv) --------

__global__ __launch_bounds__(256) void csr_build_kernel(const u32* __restrict__ binned,
                                                        const int* __restrict__ bucketOff,
                                                        int* __restrict__ col,
                                                        int* __restrict__ rowptr,
                                                        float* __restrict__ dinv,
                                                        int n, int E) {
    __shared__ int cnt[257];
    __shared__ int excl[256];
    __shared__ int wsum[4];
    __shared__ int colstage[CAP];
    const int tid   = threadIdx.x;
    const int b     = blockIdx.x;
    const int node0 = b << BSH;
    const int nNodes = min(256, n - node0);
    const int e0 = bucketOff[b], e1 = bucketOff[b + 1];
    const int ec = e1 - e0;

    for (int i = tid; i <= 256; i += 256) cnt[i] = 0;
    __syncthreads();
    for (int i = tid; i < ec; i += 256)
        atomicAdd(&cnt[binned[e0 + i] >> 24], 1);
    __syncthreads();
    const int myc = cnt[tid];
    {
        const int lane = tid & 63;
        int incl = myc;
#pragma unroll
        for (int d = 1; d < 64; d <<= 1) {
            int t = __shfl_up(incl, d);
            if (lane >= d) incl += t;
        }
        if (lane == 63) wsum[tid >> 6] = incl;
        __syncthreads();
        const int w = tid >> 6;
        int wbase = 0;
        if (w > 0) wbase += wsum[0];
        if (w > 1) wbase += wsum[1];
        if (w > 2) wbase += wsum[2];
        excl[tid] = wbase + incl - myc;
    }
    __syncthreads();
    if (tid < nNodes) {
        const int node = node0 + tid;
        rowptr[node] = e0 + excl[tid];
        dinv[node] = rsqrtf((float)(myc + 1));
    }
    if (b == 0 && tid == 0) { rowptr[n] = E; dinv[n] = 0.f; }  // sentinel weight 0
    __syncthreads();
    cnt[tid] = excl[tid];
    __syncthreads();
    if (ec <= CAP) {
        for (int i = tid; i < ec; i += 256) {
            u32 e = binned[e0 + i];
            int p = atomicAdd(&cnt[e >> 24], 1);
            colstage[p] = (int)(e & 0xffffffu);
        }
        __syncthreads();
        for (int i = tid; i < ec; i += 256) col[e0 + i] = colstage[i];
    } else {
        for (int i = tid; i < ec; i += 256) {
            u32 e = binned[e0 + i];
            int p = atomicAdd(&cnt[e >> 24], 1);
            col[e0 + p] = (int)(e & 0xffffffu);
        }
    }
}

// ---------------- agg1: channel-half split across XCDs ----------------
// Blocks with bid%8 in {0..3} (XCDs 0-3) process channels [0,64); {4..7} -> [64,128).
// Each XCD touches only its half's 128B-aligned row-halves -> per-XCD compulsory
// FETCH halves. Wave = 1 node-half: q=lane>>4 (4 edges/load), r=lane&15 (4 ch).
// graw is UNSCALED; per-edge weight dinv[u] shfl-broadcast; dinv[n]=0 sentinel.

__global__ __launch_bounds__(256) void agg1_kernel(const u16* __restrict__ g,
                                                   const int* __restrict__ rowptr,
                                                   const int* __restrict__ col,
                                                   const float* __restrict__ dinv,
                                                   const float* __restrict__ b1,
                                                   u32* __restrict__ h1, int n) {
    const int bid  = (int)blockIdx.x;
    const int half = (bid >> 2) & 1;               // bid%8: 0-3 -> 0, 4-7 -> 1
    const int grp  = (bid >> 3) * 4 + (bid & 3);   // node-group (4 nodes)
    const int wid  = threadIdx.x >> 6;
    const int lane = threadIdx.x & 63;
    const int v = grp * 4 + wid;
    if (v >= n) return;
    const int q = lane >> 4;      // which edge of the 4
    const int r = lane & 15;      // channel group within half: ch 4r..4r+3
    const int base = rowptr[v], endi = rowptr[v + 1];
    const float dv = dinv[v];
    const size_t goff = ((size_t)half << 6) + (r << 2);   // u16 offset within row

    float a0 = 0.f, a1 = 0.f, a2 = 0.f, a3 = 0.f;   // chain A (q-local)
    float b0 = 0.f, b1v = 0.f, b2v = 0.f, b3 = 0.f; // chain B
    float c0 = 0.f, c1 = 0.f, c2 = 0.f, c3 = 0.f;   // chain C
    float d0 = 0.f, d1 = 0.f, d2 = 0.f, d3 = 0.f;   // chain D
    {   // self term (weight dv), quarter 0 only
        uint2 sv = *(const uint2*)(g + ((size_t)v << 7) + goff);
        if (q == 0) {
            a0 = dv * bf_lo(sv.x); a1 = dv * bf_hi(sv.x);
            a2 = dv * bf_lo(sv.y); a3 = dv * bf_hi(sv.y);
        }
    }

    for (int c = base; c < endi; c += 64) {
        const int m = min(64, endi - c);
        const int idx = (lane < m) ? col[c + lane] : n;   // clamp -> dinv[n]=0, zero row
        const float wv = dinv[idx];
        for (int i = 0; i < m; i += 16) {
            int u0 = __shfl(idx, i + q);       float w0 = __shfl(wv, i + q);
            int u1 = __shfl(idx, i + 4 + q);   float w1 = __shfl(wv, i + 4 + q);
            int u2 = __shfl(idx, i + 8 + q);   float w2 = __shfl(wv, i + 8 + q);
            int u3 = __shfl(idx, i + 12 + q);  float w3 = __shfl(wv, i + 12 + q);
            uint2 x0 = *(const uint2*)(g + ((size_t)u0 << 7) + goff);
            uint2 x1 = *(const uint2*)(g + ((size_t)u1 << 7) + goff);
            uint2 x2 = *(const uint2*)(g + ((size_t)u2 << 7) + goff);
            uint2 x3 = *(const uint2*)(g + ((size_t)u3 << 7) + goff);
            a0 = fmaf(w0, bf_lo(x0.x), a0); a1 = fmaf(w0, bf_hi(x0.x), a1);
            a2 = fmaf(w0, bf_lo(x0.y), a2); a3 = fmaf(w0, bf_hi(x0.y), a3);
            b0 = fmaf(w1, bf_lo(x1.x), b0); b1v = fmaf(w1, bf_hi(x1.x), b1v);
            b2v = fmaf(w1, bf_lo(x1.y), b2v); b3 = fmaf(w1, bf_hi(x1.y), b3);
            c0 = fmaf(w2, bf_lo(x2.x), c0); c1 = fmaf(w2, bf_hi(x2.x), c1);
            c2 = fmaf(w2, bf_lo(x2.y), c2); c3 = fmaf(w2, bf_hi(x2.y), c3);
            d0 = fmaf(w3, bf_lo(x3.x), d0); d1 = fmaf(w3, bf_hi(x3.x), d1);
            d2 = fmaf(w3, bf_lo(x3.y), d2); d3 = fmaf(w3, bf_hi(x3.y), d3);
        }
    }
    float s0 = (a0 + b0) + (c0 + d0);
    float s1 = (a1 + b1v) + (c1 + d1);
    float s2 = (a2 + b2v) + (c2 + d2);
    float s3 = (a3 + b3) + (c3 + d3);
    s0 += __shfl_xor(s0, 16); s0 += __shfl_xor(s0, 32);
    s1 += __shfl_xor(s1, 16); s1 += __shfl_xor(s1, 32);
    s2 += __shfl_xor(s2, 16); s2 += __shfl_xor(s2, 32);
    s3 += __shfl_xor(s3, 16); s3 += __shfl_xor(s3, 32);
    if (q == 0) {
        const float4 bb = *(const float4*)&b1[(half << 6) + (r << 2)];
        float o0 = fmaxf(fmaf(dv, s0, bb.x), 0.f);
        float o1 = fmaxf(fmaf(dv, s1, bb.y), 0.f);
        float o2 = fmaxf(fmaf(dv, s2, bb.z), 0.f);
        float o3 = fmaxf(fmaf(dv, s3, bb.w), 0.f);
        uint2 pk;
        pk.x = (u32)f2bf(o0) | ((u32)f2bf(o1) << 16);
        pk.y = (u32)f2bf(o2) | ((u32)f2bf(o3) << 16);
        *(uint2*)(h1 + ((size_t)v << 6) + (half << 5) + (r << 1)) = pk;
    }
}

// agg2: g2 is dinv-scaled; 4 quarters x 4 edges/step, 4 ch/lane (uint2).
__global__ __launch_bounds__(256) void agg2_kernel(const u16* __restrict__ g2,
                                                   const int* __restrict__ rowptr,
                                                   const int* __restrict__ col,
                                                   const float* __restrict__ dinv,
                                                   const float* __restrict__ b2f,
                                                   float* __restrict__ out, int n) {
    const int wid  = threadIdx.x >> 6;
    const int lane = threadIdx.x & 63;
    const int v = blockIdx.x * 4 + wid;
    if (v >= n) return;
    const int q = lane >> 4;      // quarter: which edge of the 4
    const int r = lane & 15;      // channel group: ch 4r..4r+3
    const int base = rowptr[v], endi = rowptr[v + 1];

    float a0 = 0.f, a1 = 0.f, a2 = 0.f, a3 = 0.f;
    float b0 = 0.f, b1v = 0.f, b2v = 0.f, b3 = 0.f;
    {   // self term, quarter 0 only
        uint2 sv = *(const uint2*)(g2 + ((size_t)v << 6) + (r << 2));
        if (q == 0) {
            a0 = bf_lo(sv.x); a1 = bf_hi(sv.x);
            a2 = bf_lo(sv.y); a3 = bf_hi(sv.y);
        }
    }

    for (int c = base; c < endi; c += 64) {
        const int m = min(64, endi - c);
        const int idx = (lane < m) ? col[c + lane] : n;
        for (int i = 0; i < m; i += 8) {
            int u0 = __shfl(idx, i + q);        // edges i..i+3
            int u1 = __shfl(idx, i + 4 + q);    // edges i+4..i+7
            uint2 x0 = *(const uint2*)(g2 + ((size_t)u0 << 6) + (r << 2));
            uint2 x1 = *(const uint2*)(g2 + ((size_t)u1 << 6) + (r << 2));
            a0 += bf_lo(x0.x); a1 += bf_hi(x0.x); a2 += bf_lo(x0.y); a3 += bf_hi(x0.y);
            b0 += bf_lo(x1.x); b1v += bf_hi(x1.x); b2v += bf_lo(x1.y); b3 += bf_hi(x1.y);
        }
    }
    float s0 = a0 + b0, s1 = a1 + b1v, s2 = a2 + b2v, s3 = a3 + b3;
    s0 += __shfl_xor(s0, 16); s0 += __shfl_xor(s0, 32);
    s1 += __shfl_xor(s1, 16); s1 += __shfl_xor(s1, 32);
    s2 += __shfl_xor(s2, 16); s2 += __shfl_xor(s2, 32);
    s3 += __shfl_xor(s3, 16); s3 += __shfl_xor(s3, 32);
    if (q == 0) {
        const float dv = dinv[v];
        const float4 bb = *(const float4*)&b2f[r << 2];
        float4 o;
        o.x = fmaf(dv, s0, bb.x);
        o.y = fmaf(dv, s1, bb.y);
        o.z = fmaf(dv, s2, bb.z);
        o.w = fmaf(dv, s3, bb.w);
        *(float4*)(out + ((size_t)v << 6) + (r << 2)) = o;
    }
}

// ---------------- launch ----------------

extern "C" void kernel_launch(void* const* d_in, const int* in_sizes, int n_in,
                              void* d_out, int out_size, void* d_ws, size_t ws_size,
                              hipStream_t stream) {
    const float* x   = (const float*)d_in[0];
    const int*   ei  = (const int*)d_in[1];
    const float* W1  = (const float*)d_in[2];
    const float* b1  = (const float*)d_in[3];
    const float* W2  = (const float*)d_in[4];
    const float* b2  = (const float*)d_in[5];
    const float* Wfc = (const float*)d_in[6];
    const float* bfc = (const float*)d_in[7];
    float* out = (float*)d_out;

    const int n = in_sizes[0] / INC;
    const int E = in_sizes[1] / 2;
    const int* src = ei;
    const int* dst = ei + E;
    const int nb = (n + 255) >> BSH;

    char* w = (char*)d_ws;
    auto alloc = [&](size_t bytes) -> void* {
        void* p = (void*)w;
        w += (bytes + 255) & ~(size_t)255;
        return p;
    };
    int*   rowptr    = (int*)alloc((size_t)(n + 1) * 4);
    float* dinvp     = (float*)alloc((size_t)(n + 1) * 4);   // +1: dinv[n]=0 sentinel
    int*   col       = (int*)alloc((size_t)(E + 64) * 4);
    u32*   binned    = (u32*)alloc((size_t)E * 4);
    int*   parts     = (int*)alloc((size_t)NBMAX * HB * 4);
    int*   bucketOff = (int*)alloc((size_t)(nb + 1) * 4);
    int*   gfill     = (int*)alloc((size_t)nb * 4);
    u16*   g         = (u16*)alloc((size_t)(n + 1) * HIDC * 2);  // graw then g2, +sentinel row
    u16*   h1        = (u16*)alloc((size_t)n * HIDC * 2);        // bf16 h1
    u16*   W1t       = (u16*)alloc((size_t)HIDC * HIDC * 2);
    u16*   W2ft      = (u16*)alloc((size_t)OUTC * HIDC * 2);
    float* b2f       = (float*)alloc((size_t)OUTC * 4);

    hipMemsetAsync(gfill, 0, (size_t)nb * 4, stream);

    const int FB = HB + (HIDC * HIDC + HIDC * OUTC + OUTC + 255) / 256;
    fold_bhist_kernel<<<FB, 256, 0, stream>>>(dst, parts, E, nb,
                                              W1, W2, Wfc, b2, bfc, W1t, W2ft, b2f);
    bscan_kernel<<<1, NBMAX, 0, stream>>>(parts, bucketOff, nb);

    // merged: GEMM1 unscaled (graw = bf16(x@W1), needs only W1t) || multisplit
    const int G  = (n + 64) / 64;
    const int MS = (E + TILE - 1) / TILE;
    gemm1_ms_kernel<<<G + MS, 256, 0, stream>>>(x, W1t, g, n,
                                                src, dst, bucketOff, gfill, binned, E, nb, G);
    csr_build_kernel<<<nb, 256, 0, stream>>>(binned, bucketOff, col, rowptr, dinvp, n, E);

    // agg1: channel-half split across XCDs; h1 = bf16(relu(dinv_v*(dv*g_v + sum w_u*g_u) + b1))
    const int ng = (n + 3) / 4;
    agg1_kernel<<<8 * ((ng + 3) / 4), 256, 0, stream>>>(g, rowptr, col, dinvp, b1, (u32*)h1, n);

    // layer 2 (+FC folded): g2 = bf16((h1 @ W2f) * dinv), +zero sentinel row
    gemm2_kernel<<<(n + 64) / 64, 256, 0, stream>>>(h1, W2ft, dinvp, g, n);
    agg2_kernel<<<(n + 3) / 4, 256, 0, stream>>>(g, rowptr, col, dinvp, b2f, out, n);
}

// Round 13
// 189.853 us; speedup vs baseline: 1.0946x; 1.0946x over previous
//
#include <hip/hip_runtime.h>

#define INC  128
#define HIDC 128
#define OUTC 64

#define BSH   8        // bucket = dst >> 8 (256 nodes per bucket)
#define NBMAX 512      // supports n <= 131072
#define HB    128      // bhist blocks
#define TILE  4096     // edges per multisplit block
#define CAP   8192     // csr_build LDS col-stage capacity

typedef unsigned int  u32;
typedef unsigned short u16;
typedef short bf16x8 __attribute__((ext_vector_type(8)));
typedef float f32x4 __attribute__((ext_vector_type(4)));

static __device__ __forceinline__ u16 f2bf(float f) {
    u32 u = __builtin_bit_cast(u32, f);
    u += 0x7fffu + ((u >> 16) & 1u);
    return (u16)(u >> 16);
}
static __device__ __forceinline__ float bf_lo(u32 u) {
    return __builtin_bit_cast(float, u << 16);
}
static __device__ __forceinline__ float bf_hi(u32 u) {
    return __builtin_bit_cast(float, u & 0xffff0000u);
}

// ---------------- merged: bhist (blocks [0,HB)) + fold (blocks [HB, ...)) ----------

__global__ __launch_bounds__(256) void fold_bhist_kernel(const int* __restrict__ dst,
                                                         int* __restrict__ parts,  // [NBMAX][HB]
                                                         int E, int nb,
                                                         const float* __restrict__ W1,
                                                         const float* __restrict__ W2,
                                                         const float* __restrict__ Wfc,
                                                         const float* __restrict__ b2,
                                                         const float* __restrict__ bfc,
                                                         u16* __restrict__ W1t,
                                                         u16* __restrict__ W2ft,
                                                         float* __restrict__ b2f) {
    __shared__ int h[NBMAX];
    if (blockIdx.x < HB) {
        for (int i = threadIdx.x; i < NBMAX; i += 256) h[i] = 0;
        __syncthreads();
        const int total = HB * 256;
        for (int e = blockIdx.x * 256 + threadIdx.x; e < E; e += total)
            atomicAdd(&h[dst[e] >> BSH], 1);
        __syncthreads();
        for (int i = threadIdx.x; i < nb; i += 256) parts[i * HB + blockIdx.x] = h[i];
    } else {
        int t = (blockIdx.x - HB) * 256 + threadIdx.x;
        if (t < HIDC * HIDC) {                       // W1 transpose->bf16
            int nn = t >> 7, k = t & 127;
            W1t[nn * HIDC + k] = f2bf(W1[k * HIDC + nn]);
        } else if (t < HIDC * HIDC + HIDC * OUTC) {  // W2f fold, transposed bf16
            int u = t - HIDC * HIDC;
            int i = u >> 6, j = u & 63;
            float s = 0.f;
#pragma unroll 8
            for (int k = 0; k < OUTC; ++k) s = fmaf(W2[i * OUTC + k], Wfc[k * OUTC + j], s);
            W2ft[j * HIDC + i] = f2bf(s);
        } else if (t < HIDC * HIDC + HIDC * OUTC + OUTC) {
            int j = t - HIDC * HIDC - HIDC * OUTC;
            float s = bfc[j];
#pragma unroll 8
            for (int k = 0; k < OUTC; ++k) s = fmaf(b2[k], Wfc[k * OUTC + j], s);
            b2f[j] = s;
        }
    }
}

__global__ __launch_bounds__(512) void bscan_kernel(const int* __restrict__ parts,
                                                    int* __restrict__ bucketOff, int nb) {
    __shared__ int sums[NBMAX];
    const int tid = threadIdx.x;
    int s = 0;
    if (tid < nb) {
        const int* p = parts + tid * HB;
#pragma unroll 8
        for (int r = 0; r < HB; ++r) s += p[r];
    }
    sums[tid] = s;
    __syncthreads();
    for (int d = 1; d < NBMAX; d <<= 1) {
        int t = sums[tid];
        int a = (tid >= d) ? sums[tid - d] : 0;
        __syncthreads();
        sums[tid] = t + a;
        __syncthreads();
    }
    if (tid < nb) bucketOff[tid] = sums[tid] - s;
    if (tid == NBMAX - 1) bucketOff[nb] = sums[NBMAX - 1];
}

// ---------------- bodies for the merged GEMM1 || multisplit launch ----------------

// MFMA bf16 GEMM body: [M,128] @ [128,N] -> bf16 out.
// SCALED: rows scaled by dinv[row]; else unscaled. Row M always written ZERO (sentinel).
template <int N, bool AF32, bool SCALED>
static __device__ __forceinline__ void gemm_body(char* smem, const void* __restrict__ Aptr,
                                                 const u16* __restrict__ Wt,
                                                 const float* __restrict__ dinv,
                                                 u16* __restrict__ out, int M, int bid) {
    constexpr int K = 128;
    constexpr int NC = N / 16;
    u16* Ws = (u16*)smem;   // 16B slots: slot = n*16 + (c ^ (n&7))

    const int tid = threadIdx.x;
    for (int id = tid; id < N * K / 8; id += 256) {
        int nn = id >> 4;
        int c  = id & 15;
        uint4 v = *(const uint4*)(Wt + nn * K + c * 8);
        int slot = (nn << 4) + (c ^ (nn & 7));
        *(uint4*)((char*)Ws + slot * 16) = v;
    }

    const int wave = tid >> 6;
    const int lane = tid & 63;
    const int r0   = bid * 64 + wave * 16;
    const int arow = r0 + (lane & 15);
    const int kgrp = lane >> 4;   // 0..3
    __syncthreads();

    f32x4 acc[NC];
#pragma unroll
    for (int nc = 0; nc < NC; ++nc) acc[nc] = f32x4{0.f, 0.f, 0.f, 0.f};

#pragma unroll
    for (int kc = 0; kc < 4; ++kc) {
        bf16x8 af = {0, 0, 0, 0, 0, 0, 0, 0};
        if (arow < M) {
            if constexpr (AF32) {
                const float* ap = (const float*)Aptr + (size_t)arow * K + kc * 32 + kgrp * 8;
                float4 v0 = *(const float4*)ap;
                float4 v1 = *(const float4*)(ap + 4);
                af[0] = (short)f2bf(v0.x); af[1] = (short)f2bf(v0.y);
                af[2] = (short)f2bf(v0.z); af[3] = (short)f2bf(v0.w);
                af[4] = (short)f2bf(v1.x); af[5] = (short)f2bf(v1.y);
                af[6] = (short)f2bf(v1.z); af[7] = (short)f2bf(v1.w);
            } else {
                af = *(const bf16x8*)((const u16*)Aptr + (size_t)arow * K + kc * 32 + kgrp * 8);
            }
        }
#pragma unroll
        for (int nc = 0; nc < NC; ++nc) {
            int nn = nc * 16 + (lane & 15);
            int slot = (nn << 4) + ((kc * 4 + kgrp) ^ (nn & 7));
            bf16x8 bfr = *(const bf16x8*)((const char*)Ws + slot * 16);
            acc[nc] = __builtin_amdgcn_mfma_f32_16x16x32_bf16(af, bfr, acc[nc], 0, 0, 0);
        }
    }
    // C/D: col = lane&15, row = (lane>>4)*4 + reg
#pragma unroll
    for (int reg = 0; reg < 4; ++reg) {
        int row = r0 + (lane >> 4) * 4 + reg;
        if (row <= M) {
            float sc;
            if constexpr (SCALED) sc = (row < M) ? dinv[row] : 0.f;
            else                  sc = (row < M) ? 1.f : 0.f;
#pragma unroll
            for (int nc = 0; nc < NC; ++nc)
                out[(size_t)row * N + nc * 16 + (lane & 15)] = f2bf(acc[nc][reg] * sc);
        }
    }
}

// multisplit body: bin TILE edges by dst-bucket; binned elem = src | (dst&255)<<24
static __device__ __forceinline__ void ms_body(char* smem,
                                               const int* __restrict__ src,
                                               const int* __restrict__ dst,
                                               const int* __restrict__ bucketOff,
                                               int* __restrict__ gfill,
                                               u32* __restrict__ binned,
                                               int E, int nb, int bid) {
    int2* buf   = (int2*)smem;                       // TILE*8 = 32768
    int* hist   = (int*)(smem + TILE * 8);           // NBMAX ints
    int* sbase  = hist + NBMAX;
    int* cursor = sbase + NBMAX;
    int* gposs  = cursor + NBMAX;
    int* wsum   = gposs + NBMAX;                     // 4 ints
    const int tid  = threadIdx.x;
    const int base = bid * TILE;
    const int cnt  = min(TILE, E - base);

    for (int i = tid; i < NBMAX; i += 256) hist[i] = 0;
    __syncthreads();

    int ls[16], ld[16], dg[16];
#pragma unroll
    for (int k = 0; k < 16; ++k) {
        int idx = tid + k * 256;
        if (idx < cnt) {
            ls[k] = src[base + idx];
            ld[k] = dst[base + idx];
            dg[k] = ld[k] >> BSH;
            atomicAdd(&hist[dg[k]], 1);
        } else dg[k] = -1;
    }
    __syncthreads();
    {
        const int a = hist[2 * tid], b = hist[2 * tid + 1];
        const int s = a + b;
        const int lane = tid & 63;
        int incl = s;
#pragma unroll
        for (int d = 1; d < 64; d <<= 1) {
            int t = __shfl_up(incl, d);
            if (lane >= d) incl += t;
        }
        if (lane == 63) wsum[tid >> 6] = incl;
        __syncthreads();
        const int w = tid >> 6;
        int wbase = 0;
        if (w > 0) wbase += wsum[0];
        if (w > 1) wbase += wsum[1];
        if (w > 2) wbase += wsum[2];
        const int excl = wbase + incl - s;
        sbase[2 * tid] = excl;          cursor[2 * tid] = excl;
        sbase[2 * tid + 1] = excl + a;  cursor[2 * tid + 1] = excl + a;
    }
    __syncthreads();
#pragma unroll
    for (int k = 0; k < 16; ++k) {
        if (dg[k] >= 0) {
            int p = atomicAdd(&cursor[dg[k]], 1);
            buf[p] = make_int2(ls[k], ld[k]);
        }
    }
    __syncthreads();
    for (int d = tid; d < nb; d += 256) {
        int c = cursor[d] - sbase[d];
        gposs[d] = (c > 0) ? atomicAdd(&gfill[d], c) : 0;
    }
    __syncthreads();
    for (int idx = tid; idx < cnt; idx += 256) {
        int2 e = buf[idx];
        int d = e.y >> BSH;
        binned[bucketOff[d] + gposs[d] + (idx - sbase[d])] =
            (u32)e.x | ((u32)(e.y & 255) << 24);
    }
}

#define SMEM_MERGED 41008   // max(gemm 32768, ms 32768+4*NBMAX*4+16), 16-aligned

// merged: GEMM1 (unscaled -> graw) in blocks [0,G); multisplit in blocks [G, G+MS)
__global__ __launch_bounds__(256) void gemm1_ms_kernel(const float* __restrict__ x,
                                                       const u16* __restrict__ W1t,
                                                       u16* __restrict__ graw, int M,
                                                       const int* __restrict__ src,
                                                       const int* __restrict__ dst,
                                                       const int* __restrict__ bucketOff,
                                                       int* __restrict__ gfill,
                                                       u32* __restrict__ binned,
                                                       int E, int nb, int G) {
    __shared__ __align__(16) char smem[SMEM_MERGED];
    const int b = (int)blockIdx.x;
    if (b < G) gemm_body<HIDC, true, false>(smem, x, W1t, nullptr, graw, M, b);
    else       ms_body(smem, src, dst, bucketOff, gfill, binned, E, nb, b - G);
}

__global__ __launch_bounds__(256) void gemm2_kernel(const u16* __restrict__ h1,
                                                    const u16* __restrict__ W2ft,
                                                    const float* __restrict__ dinv,
                                                    u16* __restrict__ g2, int M) {
    __shared__ __align__(16) char smem[OUTC * 128 * 2];
    gemm_body<OUTC, false, true>(smem, h1, W2ft, dinv, g2, M, (int)blockIdx.x);
}

// ---------------- csr_build: per-bucket node grouping (col + rowptr + dinv) --------

__global__ __launch_bounds__(256) void csr_build_kernel(const u32* __restrict__ binned,
                                                        const int* __restrict__ bucketOff,
                                                        int* __restrict__ col,
                                                        int* __restrict__ rowptr,
                                                        float* __restrict__ dinv,
                                                        int n, int E) {
    __shared__ int cnt[257];
    __shared__ int excl[256];
    __shared__ int wsum[4];
    __shared__ int colstage[CAP];
    const int tid   = threadIdx.x;
    const int b     = blockIdx.x;
    const int node0 = b << BSH;
    const int nNodes = min(256, n - node0);
    const int e0 = bucketOff[b], e1 = bucketOff[b + 1];
    const int ec = e1 - e0;

    for (int i = tid; i <= 256; i += 256) cnt[i] = 0;
    __syncthreads();
    for (int i = tid; i < ec; i += 256)
        atomicAdd(&cnt[binned[e0 + i] >> 24], 1);
    __syncthreads();
    const int myc = cnt[tid];
    {
        const int lane = tid & 63;
        int incl = myc;
#pragma unroll
        for (int d = 1; d < 64; d <<= 1) {
            int t = __shfl_up(incl, d);
            if (lane >= d) incl += t;
        }
        if (lane == 63) wsum[tid >> 6] = incl;
        __syncthreads();
        const int w = tid >> 6;
        int wbase = 0;
        if (w > 0) wbase += wsum[0];
        if (w > 1) wbase += wsum[1];
        if (w > 2) wbase += wsum[2];
        excl[tid] = wbase + incl - myc;
    }
    __syncthreads();
    if (tid < nNodes) {
        const int node = node0 + tid;
        rowptr[node] = e0 + excl[tid];
        dinv[node] = rsqrtf((float)(myc + 1));
    }
    if (b == 0 && tid == 0) { rowptr[n] = E; dinv[n] = 0.f; }  // sentinel weight 0
    __syncthreads();
    cnt[tid] = excl[tid];
    __syncthreads();
    if (ec <= CAP) {
        for (int i = tid; i < ec; i += 256) {
            u32 e = binned[e0 + i];
            int p = atomicAdd(&cnt[e >> 24], 1);
            colstage[p] = (int)(e & 0xffffffu);
        }
        __syncthreads();
        for (int i = tid; i < ec; i += 256) col[e0 + i] = colstage[i];
    } else {
        for (int i = tid; i < ec; i += 256) {
            u32 e = binned[e0 + i];
            int p = atomicAdd(&cnt[e >> 24], 1);
            col[e0 + p] = (int)(e & 0xffffffu);
        }
    }
}

// ---------------- aggregation ----------------
// agg1: graw is UNSCALED; per-edge weight dinv[u] gathered once per 64-chunk and
// shfl-broadcast with the index. 2 halves x 2 edges/step, 4 ch/lane.

__global__ __launch_bounds__(256) void agg1_kernel(const u16* __restrict__ g,
                                                   const int* __restrict__ rowptr,
                                                   const int* __restrict__ col,
                                                   const float* __restrict__ dinv,
                                                   const float* __restrict__ b1,
                                                   u32* __restrict__ h1, int n) {
    const int wid  = threadIdx.x >> 6;
    const int lane = threadIdx.x & 63;
    const int v = blockIdx.x * 4 + wid;
    if (v >= n) return;
    const int h = lane >> 5;      // half: which edge of the pair
    const int r = lane & 31;      // channel group: ch 4r..4r+3
    const int base = rowptr[v], endi = rowptr[v + 1];
    const float dv = dinv[v];

    float a0 = 0.f, a1 = 0.f, a2 = 0.f, a3 = 0.f;   // chain A
    float b0 = 0.f, b1v = 0.f, b2v = 0.f, b3 = 0.f; // chain B
    {   // self term (weight dv), half 0 only
        uint2 sv = *(const uint2*)(g + ((size_t)v << 7) + (r << 2));
        if (h == 0) {
            a0 = dv * bf_lo(sv.x); a1 = dv * bf_hi(sv.x);
            a2 = dv * bf_lo(sv.y); a3 = dv * bf_hi(sv.y);
        }
    }

    for (int c = base; c < endi; c += 64) {
        const int m = min(64, endi - c);
        const int idx = (lane < m) ? col[c + lane] : n;   // clamp -> dinv[n]=0, zero row
        const float wv = dinv[idx];
        for (int i = 0; i < m; i += 8) {
            int u0 = __shfl(idx, i + h);      float w0 = __shfl(wv, i + h);
            int u1 = __shfl(idx, i + 2 + h);  float w1 = __shfl(wv, i + 2 + h);
            int u2 = __shfl(idx, i + 4 + h);  float w2 = __shfl(wv, i + 4 + h);
            int u3 = __shfl(idx, i + 6 + h);  float w3 = __shfl(wv, i + 6 + h);
            uint2 x0 = *(const uint2*)(g + ((size_t)u0 << 7) + (r << 2));
            uint2 x1 = *(const uint2*)(g + ((size_t)u1 << 7) + (r << 2));
            uint2 x2 = *(const uint2*)(g + ((size_t)u2 << 7) + (r << 2));
            uint2 x3 = *(const uint2*)(g + ((size_t)u3 << 7) + (r << 2));
            a0 = fmaf(w0, bf_lo(x0.x), a0); a1 = fmaf(w0, bf_hi(x0.x), a1);
            a2 = fmaf(w0, bf_lo(x0.y), a2); a3 = fmaf(w0, bf_hi(x0.y), a3);
            b0 = fmaf(w1, bf_lo(x1.x), b0); b1v = fmaf(w1, bf_hi(x1.x), b1v);
            b2v = fmaf(w1, bf_lo(x1.y), b2v); b3 = fmaf(w1, bf_hi(x1.y), b3);
            a0 = fmaf(w2, bf_lo(x2.x), a0); a1 = fmaf(w2, bf_hi(x2.x), a1);
            a2 = fmaf(w2, bf_lo(x2.y), a2); a3 = fmaf(w2, bf_hi(x2.y), a3);
            b0 = fmaf(w3, bf_lo(x3.x), b0); b1v = fmaf(w3, bf_hi(x3.x), b1v);
            b2v = fmaf(w3, bf_lo(x3.y), b2v); b3 = fmaf(w3, bf_hi(x3.y), b3);
        }
    }
    float s0 = a0 + b0, s1 = a1 + b1v, s2 = a2 + b2v, s3 = a3 + b3;
    s0 += __shfl_xor(s0, 32);
    s1 += __shfl_xor(s1, 32);
    s2 += __shfl_xor(s2, 32);
    s3 += __shfl_xor(s3, 32);
    if (h == 0) {
        const float4 bb = *(const float4*)&b1[r << 2];
        float o0 = fmaxf(fmaf(dv, s0, bb.x), 0.f);
        float o1 = fmaxf(fmaf(dv, s1, bb.y), 0.f);
        float o2 = fmaxf(fmaf(dv, s2, bb.z), 0.f);
        float o3 = fmaxf(fmaf(dv, s3, bb.w), 0.f);
        uint2 pk;
        pk.x = (u32)f2bf(o0) | ((u32)f2bf(o1) << 16);
        pk.y = (u32)f2bf(o2) | ((u32)f2bf(o3) << 16);
        *(uint2*)(h1 + ((size_t)v << 6) + (r << 1)) = pk;
    }
}

// agg2: g2 is dinv-scaled; 4 quarters x 4 edges/step, 4 ch/lane (uint2).
__global__ __launch_bounds__(256) void agg2_kernel(const u16* __restrict__ g2,
                                                   const int* __restrict__ rowptr,
                                                   const int* __restrict__ col,
                                                   const float* __restrict__ dinv,
                                                   const float* __restrict__ b2f,
                                                   float* __restrict__ out, int n) {
    const int wid  = threadIdx.x >> 6;
    const int lane = threadIdx.x & 63;
    const int v = blockIdx.x * 4 + wid;
    if (v >= n) return;
    const int q = lane >> 4;      // quarter: which edge of the 4
    const int r = lane & 15;      // channel group: ch 4r..4r+3
    const int base = rowptr[v], endi = rowptr[v + 1];

    float a0 = 0.f, a1 = 0.f, a2 = 0.f, a3 = 0.f;
    float b0 = 0.f, b1v = 0.f, b2v = 0.f, b3 = 0.f;
    {   // self term, quarter 0 only
        uint2 sv = *(const uint2*)(g2 + ((size_t)v << 6) + (r << 2));
        if (q == 0) {
            a0 = bf_lo(sv.x); a1 = bf_hi(sv.x);
            a2 = bf_lo(sv.y); a3 = bf_hi(sv.y);
        }
    }

    for (int c = base; c < endi; c += 64) {
        const int m = min(64, endi - c);
        const int idx = (lane < m) ? col[c + lane] : n;
        for (int i = 0; i < m; i += 8) {
            int u0 = __shfl(idx, i + q);        // edges i..i+3
            int u1 = __shfl(idx, i + 4 + q);    // edges i+4..i+7
            uint2 x0 = *(const uint2*)(g2 + ((size_t)u0 << 6) + (r << 2));
            uint2 x1 = *(const uint2*)(g2 + ((size_t)u1 << 6) + (r << 2));
            a0 += bf_lo(x0.x); a1 += bf_hi(x0.x); a2 += bf_lo(x0.y); a3 += bf_hi(x0.y);
            b0 += bf_lo(x1.x); b1v += bf_hi(x1.x); b2v += bf_lo(x1.y); b3 += bf_hi(x1.y);
        }
    }
    float s0 = a0 + b0, s1 = a1 + b1v, s2 = a2 + b2v, s3 = a3 + b3;
    s0 += __shfl_xor(s0, 16); s0 += __shfl_xor(s0, 32);
    s1 += __shfl_xor(s1, 16); s1 += __shfl_xor(s1, 32);
    s2 += __shfl_xor(s2, 16); s2 += __shfl_xor(s2, 32);
    s3 += __shfl_xor(s3, 16); s3 += __shfl_xor(s3, 32);
    if (q == 0) {
        const float dv = dinv[v];
        const float4 bb = *(const float4*)&b2f[r << 2];
        float4 o;
        o.x = fmaf(dv, s0, bb.x);
        o.y = fmaf(dv, s1, bb.y);
        o.z = fmaf(dv, s2, bb.z);
        o.w = fmaf(dv, s3, bb.w);
        *(float4*)(out + ((size_t)v << 6) + (r << 2)) = o;
    }
}

// ---------------- launch ----------------

extern "C" void kernel_launch(void* const* d_in, const int* in_sizes, int n_in,
                              void* d_out, int out_size, void* d_ws, size_t ws_size,
                              hipStream_t stream) {
    const float* x   = (const float*)d_in[0];
    const int*   ei  = (const int*)d_in[1];
    const float* W1  = (const float*)d_in[2];
    const float* b1  = (const float*)d_in[3];
    const float* W2  = (const float*)d_in[4];
    const float* b2  = (const float*)d_in[5];
    const float* Wfc = (const float*)d_in[6];
    const float* bfc = (const float*)d_in[7];
    float* out = (float*)d_out;

    const int n = in_sizes[0] / INC;
    const int E = in_sizes[1] / 2;
    const int* src = ei;
    const int* dst = ei + E;
    const int nb = (n + 255) >> BSH;

    char* w = (char*)d_ws;
    auto alloc = [&](size_t bytes) -> void* {
        void* p = (void*)w;
        w += (bytes + 255) & ~(size_t)255;
        return p;
    };
    int*   rowptr    = (int*)alloc((size_t)(n + 1) * 4);
    float* dinvp     = (float*)alloc((size_t)(n + 1) * 4);   // +1: dinv[n]=0 sentinel
    int*   col       = (int*)alloc((size_t)(E + 64) * 4);
    u32*   binned    = (u32*)alloc((size_t)E * 4);
    int*   parts     = (int*)alloc((size_t)NBMAX * HB * 4);
    int*   bucketOff = (int*)alloc((size_t)(nb + 1) * 4);
    int*   gfill     = (int*)alloc((size_t)nb * 4);
    u16*   g         = (u16*)alloc((size_t)(n + 1) * HIDC * 2);  // graw then g2, +sentinel row
    u16*   h1        = (u16*)alloc((size_t)n * HIDC * 2);        // bf16 h1
    u16*   W1t       = (u16*)alloc((size_t)HIDC * HIDC * 2);
    u16*   W2ft      = (u16*)alloc((size_t)OUTC * HIDC * 2);
    float* b2f       = (float*)alloc((size_t)OUTC * 4);

    hipMemsetAsync(gfill, 0, (size_t)nb * 4, stream);

    const int FB = HB + (HIDC * HIDC + HIDC * OUTC + OUTC + 255) / 256;
    fold_bhist_kernel<<<FB, 256, 0, stream>>>(dst, parts, E, nb,
                                              W1, W2, Wfc, b2, bfc, W1t, W2ft, b2f);
    bscan_kernel<<<1, NBMAX, 0, stream>>>(parts, bucketOff, nb);

    // merged: GEMM1 unscaled (graw = bf16(x@W1), needs only W1t) || multisplit
    const int G  = (n + 64) / 64;
    const int MS = (E + TILE - 1) / TILE;
    gemm1_ms_kernel<<<G + MS, 256, 0, stream>>>(x, W1t, g, n,
                                                src, dst, bucketOff, gfill, binned, E, nb, G);
    csr_build_kernel<<<nb, 256, 0, stream>>>(binned, bucketOff, col, rowptr, dinvp, n, E);

    // agg1 applies per-edge dinv[u] and dinv[v]: h1 = bf16(relu(dinv_v*(sum w_u*graw_u) + b1))
    agg1_kernel<<<(n + 3) / 4, 256, 0, stream>>>(g, rowptr, col, dinvp, b1, (u32*)h1, n);

    // layer 2 (+FC folded): g2 = bf16((h1 @ W2f) * dinv), +zero sentinel row
    gemm2_kernel<<<(n + 64) / 64, 256, 0, stream>>>(h1, W2ft, dinvp, g, n);
    agg2_kernel<<<(n + 3) / 4, 256, 0, stream>>>(g, rowptr, col, dinvp, b2f, out, n);
}